// Round 1
// baseline (844.548 us; speedup 1.0000x reference)
//
#include <hip/hip_runtime.h>

#define NH_ 8
#define NL_ 4
#define NP_ 4
#define DH_ 32
#define CD_ 256
#define B_  4
#define NQ_ 8000
#define S_  19947

// ---------------------------------------------------------------------------
// Tiled fp32 GEMM:  C[m,n] = sum_k A[m,k] * W[n,k] + bias[n]
// A: [M,K] row-major, W: [N,K] row-major (torch Linear weight layout), K=256.
// BM=BN=128, BK=16, 256 threads, 8x8 register tile per thread.
// ---------------------------------------------------------------------------
template<int BM, int BN, int BK>
__global__ __launch_bounds__(256)
void gemm_bt(const float* __restrict__ A, const float* __restrict__ W,
             const float* __restrict__ bias, float* __restrict__ Cmat,
             int M, int N, int K)
{
    __shared__ float As[BK][BM + 4];
    __shared__ float Bs[BK][BN + 4];

    const int tid = threadIdx.x;
    const int m0 = blockIdx.x * BM;
    const int n0 = blockIdx.y * BN;
    const int tx = tid & 15;   // n-direction, 16 threads
    const int ty = tid >> 4;   // m-direction, 16 threads

    float acc[8][8];
#pragma unroll
    for (int i = 0; i < 8; ++i)
#pragma unroll
        for (int j = 0; j < 8; ++j) acc[i][j] = 0.f;

    const int lr0 = tid >> 2;  // 0..63 (row within tile)
    const int lf  = tid & 3;   // 0..3  (float4 slot within BK=16)

    for (int k0 = 0; k0 < K; k0 += BK) {
#pragma unroll
        for (int half = 0; half < 2; ++half) {
            const int r = lr0 + half * 64;
            float4 va = make_float4(0.f, 0.f, 0.f, 0.f);
            if (m0 + r < M)
                va = *reinterpret_cast<const float4*>(&A[(size_t)(m0 + r) * K + k0 + lf * 4]);
            As[lf * 4 + 0][r] = va.x;
            As[lf * 4 + 1][r] = va.y;
            As[lf * 4 + 2][r] = va.z;
            As[lf * 4 + 3][r] = va.w;

            float4 vb = make_float4(0.f, 0.f, 0.f, 0.f);
            if (n0 + r < N)
                vb = *reinterpret_cast<const float4*>(&W[(size_t)(n0 + r) * K + k0 + lf * 4]);
            Bs[lf * 4 + 0][r] = vb.x;
            Bs[lf * 4 + 1][r] = vb.y;
            Bs[lf * 4 + 2][r] = vb.z;
            Bs[lf * 4 + 3][r] = vb.w;
        }
        __syncthreads();

#pragma unroll
        for (int kk = 0; kk < BK; ++kk) {
            float a[8], b[8];
            *reinterpret_cast<float4*>(&a[0]) = *reinterpret_cast<const float4*>(&As[kk][ty * 8]);
            *reinterpret_cast<float4*>(&a[4]) = *reinterpret_cast<const float4*>(&As[kk][ty * 8 + 4]);
            *reinterpret_cast<float4*>(&b[0]) = *reinterpret_cast<const float4*>(&Bs[kk][tx * 8]);
            *reinterpret_cast<float4*>(&b[4]) = *reinterpret_cast<const float4*>(&Bs[kk][tx * 8 + 4]);
#pragma unroll
            for (int i = 0; i < 8; ++i)
#pragma unroll
                for (int j = 0; j < 8; ++j)
                    acc[i][j] += a[i] * b[j];
        }
        __syncthreads();
    }

    // epilogue: C = acc + bias
#pragma unroll
    for (int i = 0; i < 8; ++i) {
        const int m = m0 + ty * 8 + i;
        if (m >= M) continue;
#pragma unroll
        for (int j = 0; j < 8; j += 4) {
            const int n = n0 + tx * 8 + j;
            float4 v;
            v.x = acc[i][j + 0] + bias[n + 0];
            v.y = acc[i][j + 1] + bias[n + 1];
            v.z = acc[i][j + 2] + bias[n + 2];
            v.w = acc[i][j + 3] + bias[n + 3];
            *reinterpret_cast<float4*>(&Cmat[(size_t)m * N + n]) = v;
        }
    }
}

// ---------------------------------------------------------------------------
// Fused softmax + bilinear sampling + attention-weighted accumulation.
// One block per (b,q); 256 threads = 8 heads x 32 dh-lanes.
// value:  [B, S, NH, DH]   (projected)
// off:    [B, Nq, NH, NL, NP, 2]
// attn:   [B, Nq, NH, 16]  (raw logits)
// refp:   [B, Nq, NL, 2]
// outS:   [B, Nq, 256]     (sampled, pre-output-projection)
// ---------------------------------------------------------------------------
__global__ __launch_bounds__(256)
void sampler(const float* __restrict__ value,
             const float* __restrict__ off,
             const float* __restrict__ attn,
             const float* __restrict__ refp,
             float* __restrict__ outS)
{
    const int bq = blockIdx.x;            // 0 .. B*Nq-1
    const int b  = bq / NQ_;
    const int h  = threadIdx.x >> 5;      // 0..7
    const int d  = threadIdx.x & 31;      // 0..31

    const float* offp = off  + ((size_t)bq * NH_ + h) * (NL_ * NP_ * 2);
    const float* logp = attn + ((size_t)bq * NH_ + h) * (NL_ * NP_);
    const float* refb = refp + (size_t)bq * (NL_ * 2);

    // softmax over 16 logits (computed redundantly per lane; broadcast loads)
    float lg[16];
    float mx = -1e30f;
#pragma unroll
    for (int i = 0; i < 16; ++i) { lg[i] = logp[i]; mx = fmaxf(mx, lg[i]); }
    float ssum = 0.f;
#pragma unroll
    for (int i = 0; i < 16; ++i) { lg[i] = __expf(lg[i] - mx); ssum += lg[i]; }
    const float rs = 1.f / ssum;

    const int Hs[4] = {100, 50, 25, 13};
    const int Ws[4] = {150, 75, 38, 19};
    const int St[4] = {0, 15000, 18750, 19700};

    const float* valb = value + (size_t)b * S_ * CD_ + h * DH_ + d;

    float acc = 0.f;
#pragma unroll
    for (int l = 0; l < NL_; ++l) {
        const float rx = refb[l * 2 + 0];
        const float ry = refb[l * 2 + 1];
        const int   Hl = Hs[l], Wl = Ws[l];
        const float fW = (float)Wl, fH = (float)Hl;
        const float* vl = valb + (size_t)St[l] * CD_;
#pragma unroll
        for (int p = 0; p < NP_; ++p) {
            const float ox = offp[(l * 4 + p) * 2 + 0];
            const float oy = offp[(l * 4 + p) * 2 + 1];
            const float lx = rx + ox / fW;        // matches reference op order
            const float ly = ry + oy / fH;
            const float x = lx * fW - 0.5f;
            const float y = ly * fH - 0.5f;
            const float x0 = floorf(x), y0 = floorf(y);
            const float wx1 = x - x0, wy1 = y - y0;
            const float wx0 = 1.f - wx1, wy0 = 1.f - wy1;
            const int ix0 = (int)x0, iy0 = (int)y0;
            const float aw = lg[l * 4 + p] * rs;

            const float w00 = wx0 * wy0 * aw;
            const float w10 = wx1 * wy0 * aw;
            const float w01 = wx0 * wy1 * aw;
            const float w11 = wx1 * wy1 * aw;

            const bool vx0 = (ix0 >= 0) && (ix0 < Wl);
            const bool vx1 = (ix0 + 1 >= 0) && (ix0 + 1 < Wl);
            if (iy0 >= 0 && iy0 < Hl) {
                const float* row = vl + (size_t)(iy0 * Wl) * CD_;
                if (vx0) acc += w00 * row[(size_t)ix0 * CD_];
                if (vx1) acc += w10 * row[(size_t)(ix0 + 1) * CD_];
            }
            if (iy0 + 1 >= 0 && iy0 + 1 < Hl) {
                const float* row = vl + (size_t)((iy0 + 1) * Wl) * CD_;
                if (vx0) acc += w01 * row[(size_t)ix0 * CD_];
                if (vx1) acc += w11 * row[(size_t)(ix0 + 1) * CD_];
            }
        }
    }

    outS[(size_t)bq * CD_ + h * DH_ + d] = acc;
}

// ---------------------------------------------------------------------------
extern "C" void kernel_launch(void* const* d_in, const int* in_sizes, int n_in,
                              void* d_out, int out_size, void* d_ws, size_t ws_size,
                              hipStream_t stream)
{
    const float* query        = (const float*)d_in[0];   // [B,Nq,256]
    const float* value_levels = (const float*)d_in[1];   // [B,S,256]
    const float* refp         = (const float*)d_in[2];   // [B,Nq,NL,2]
    // d_in[3] spatial_shapes: compile-time constants, ignored
    const float* W_off  = (const float*)d_in[4];
    const float* b_off  = (const float*)d_in[5];
    const float* W_attn = (const float*)d_in[6];
    const float* b_attn = (const float*)d_in[7];
    const float* W_val  = (const float*)d_in[8];
    const float* b_val  = (const float*)d_in[9];
    const float* W_out  = (const float*)d_in[10];
    const float* b_out  = (const float*)d_in[11];

    float* out = (float*)d_out;
    float* ws  = (float*)d_ws;

    float* ws_value = ws;                                       // B*S*256
    float* ws_off   = ws_value + (size_t)B_ * S_  * CD_;        // B*Nq*256
    float* ws_attn  = ws_off   + (size_t)B_ * NQ_ * CD_;        // B*Nq*128
    float* ws_samp  = ws_attn  + (size_t)B_ * NQ_ * 128;        // B*Nq*256

    const dim3 blk(256);
    const int M_val = B_ * S_;     // 79788
    const int M_q   = B_ * NQ_;    // 32000

    // 1) value projection -> ws_value
    gemm_bt<128, 128, 16><<<dim3((M_val + 127) / 128, 2), blk, 0, stream>>>(
        value_levels, W_val, b_val, ws_value, M_val, 256, 256);

    // 2) offsets projection -> ws_off
    gemm_bt<128, 128, 16><<<dim3(M_q / 128, 2), blk, 0, stream>>>(
        query, W_off, b_off, ws_off, M_q, 256, 256);

    // 3) attention logits projection -> ws_attn
    gemm_bt<128, 128, 16><<<dim3(M_q / 128, 1), blk, 0, stream>>>(
        query, W_attn, b_attn, ws_attn, M_q, 128, 256);

    // 4) fused softmax + bilinear sampling -> ws_samp
    sampler<<<dim3(B_ * NQ_), blk, 0, stream>>>(
        ws_value, ws_off, ws_attn, refp, ws_samp);

    // 5) output projection -> d_out
    gemm_bt<128, 128, 16><<<dim3(M_q / 128, 2), blk, 0, stream>>>(
        ws_samp, W_out, b_out, out, M_q, 256, 256);
}

// Round 7
// 460.280 us; speedup vs baseline: 1.8349x; 1.8349x over previous
//
#include <hip/hip_runtime.h>

#define NH_ 8
#define NL_ 4
#define NP_ 4
#define DH_ 32
#define CD_ 256
#define B_  4
#define NQ_ 8000
#define S_  19947

typedef __attribute__((ext_vector_type(8))) _Float16 f16x8;
typedef __attribute__((ext_vector_type(4))) float    f32x4;

// ---------------------------------------------------------------------------
// MFMA f16 GEMM:  C[m,n] = sum_k A[m,k] * W[n,k] + bias[n],  K = 256 fixed.
// A: [M,256] fp32 row-major, W: [N,256] fp32 row-major (torch Linear layout).
// BM=BN=128, BK=64, 256 threads = 4 waves, each wave a 64x64 quadrant
// (4x4 grid of 16x16x32 MFMA frags, fp32 accum).
// Staging: fp32 global -> regs -> cvt f16 -> XOR-swizzled LDS
// (byte ^= (row&7)<<4) so frag ds_read_b128 is ~conflict-free (G4).
// A/B fragments use the SAME k-index structure (row = base + lane&15,
// k = (lane>>4)*8 + j), so any k-order mismatch vs HW cancels in sum-over-k.
// C/D: col = lane&15, row = (lane>>4)*4 + reg  [measured m89/m91].
// ---------------------------------------------------------------------------
__global__ __launch_bounds__(256)
void gemm_mfma(const float* __restrict__ A, const float* __restrict__ W,
               const float* __restrict__ bias, float* __restrict__ Cmat,
               int M, int N)
{
    __shared__ __align__(16) unsigned short As[128 * 64];
    __shared__ __align__(16) unsigned short Bs[128 * 64];

    const int tid  = threadIdx.x;
    const int m0   = blockIdx.x * 128;
    const int n0   = blockIdx.y * 128;
    const int wave = tid >> 6;
    const int lane = tid & 63;
    const int wm   = (wave >> 1) * 64;
    const int wn   = (wave & 1) * 64;
    const int lr   = lane & 15;       // m / n within frag
    const int lg   = lane >> 4;       // k-group 0..3

    f32x4 acc[4][4];
#pragma unroll
    for (int i = 0; i < 4; ++i)
#pragma unroll
        for (int j = 0; j < 4; ++j) {
            f32x4 z = {0.f, 0.f, 0.f, 0.f};
            acc[i][j] = z;
        }

    const int srow = tid >> 4;        // 0..15
    const int scol = (tid & 15) * 4;  // k element base 0,4,..,60

    for (int k0 = 0; k0 < 256; k0 += 64) {
#pragma unroll
        for (int pass = 0; pass < 8; ++pass) {
            const int r = srow + pass * 16;
            const int byteoff = r * 128 + ((scol * 2) ^ ((r & 7) << 4));

            float4 va = make_float4(0.f, 0.f, 0.f, 0.f);
            if (m0 + r < M)
                va = *reinterpret_cast<const float4*>(&A[(size_t)(m0 + r) * 256 + k0 + scol]);
            union { _Float16 h[4]; uint2 u; } pa;
            pa.h[0] = (_Float16)va.x; pa.h[1] = (_Float16)va.y;
            pa.h[2] = (_Float16)va.z; pa.h[3] = (_Float16)va.w;
            *reinterpret_cast<uint2*>(reinterpret_cast<char*>(As) + byteoff) = pa.u;

            float4 vb = make_float4(0.f, 0.f, 0.f, 0.f);
            if (n0 + r < N)
                vb = *reinterpret_cast<const float4*>(&W[(size_t)(n0 + r) * 256 + k0 + scol]);
            union { _Float16 h[4]; uint2 u; } pb;
            pb.h[0] = (_Float16)vb.x; pb.h[1] = (_Float16)vb.y;
            pb.h[2] = (_Float16)vb.z; pb.h[3] = (_Float16)vb.w;
            *reinterpret_cast<uint2*>(reinterpret_cast<char*>(Bs) + byteoff) = pb.u;
        }
        __syncthreads();

#pragma unroll
        for (int ks = 0; ks < 2; ++ks) {          // two K=32 sub-steps
            const int col = ks * 4 + lg;          // 16B column 0..7
            f16x8 af[4], bf[4];
#pragma unroll
            for (int i = 0; i < 4; ++i) {
                const int m = wm + i * 16 + lr;
                af[i] = *reinterpret_cast<const f16x8*>(
                    reinterpret_cast<const char*>(As) + m * 128 + ((col * 16) ^ ((m & 7) << 4)));
            }
#pragma unroll
            for (int j = 0; j < 4; ++j) {
                const int n = wn + j * 16 + lr;
                bf[j] = *reinterpret_cast<const f16x8*>(
                    reinterpret_cast<const char*>(Bs) + n * 128 + ((col * 16) ^ ((n & 7) << 4)));
            }
#pragma unroll
            for (int i = 0; i < 4; ++i)
#pragma unroll
                for (int j = 0; j < 4; ++j)
                    acc[i][j] = __builtin_amdgcn_mfma_f32_16x16x32_f16(af[i], bf[j], acc[i][j], 0, 0, 0);
        }
        __syncthreads();
    }

    // epilogue: C = acc + bias
#pragma unroll
    for (int j = 0; j < 4; ++j) {
        const int n  = n0 + wn + j * 16 + lr;
        const float bn = bias[n];
#pragma unroll
        for (int i = 0; i < 4; ++i) {
            const int mb = m0 + wm + i * 16 + lg * 4;
#pragma unroll
            for (int r = 0; r < 4; ++r) {
                const int m = mb + r;
                if (m < M) Cmat[(size_t)m * N + n] = acc[i][j][r] + bn;
            }
        }
    }
}

// ---------------------------------------------------------------------------
// Fused softmax + bilinear sampling, two-phase.
// Phase 1: 128 threads = 8 heads x 16 points -> weights/indices in LDS.
// Phase 2: 256 threads = 8 heads x 32 dh-lanes -> gathers + FMAs.
// ---------------------------------------------------------------------------
__global__ __launch_bounds__(256)
void sampler(const float* __restrict__ value,
             const float* __restrict__ off,
             const float* __restrict__ attn,
             const float* __restrict__ refp,
             float* __restrict__ outS)
{
    __shared__ __align__(16) float swi[NH_][16][8];  // [0..3]=w, [4..7]=idx(int)

    const int bq = blockIdx.x;            // 0 .. B*Nq-1
    const int b  = bq / NQ_;
    const int tid = threadIdx.x;

    if (tid < 128) {
        const int h = tid >> 4;           // 0..7
        const int p = tid & 15;           // 0..15 = l*4 + pp
        const int l = p >> 2;

        const float logit = attn[((size_t)bq * NH_ + h) * 16 + p];

        float mx = logit;
#pragma unroll
        for (int m = 8; m >= 1; m >>= 1) mx = fmaxf(mx, __shfl_xor(mx, m, 64));
        float e = __expf(logit - mx);
        float ssum = e;
#pragma unroll
        for (int m = 8; m >= 1; m >>= 1) ssum += __shfl_xor(ssum, m, 64);
        const float aw = e / ssum;

        const int   Hs[4] = {100, 50, 25, 13};
        const int   Ws[4] = {150, 75, 38, 19};
        const int   St[4] = {0, 15000, 18750, 19700};
        const int   Hl = Hs[l], Wl = Ws[l], base = St[l];
        const float fW = (float)Wl, fH = (float)Hl;

        const float rx = refp[((size_t)bq * NL_ + l) * 2 + 0];
        const float ry = refp[((size_t)bq * NL_ + l) * 2 + 1];
        const float ox = off[(((size_t)bq * NH_ + h) * 16 + p) * 2 + 0];
        const float oy = off[(((size_t)bq * NH_ + h) * 16 + p) * 2 + 1];

        const float lx = rx + ox / fW;    // reference op order
        const float ly = ry + oy / fH;
        const float x = lx * fW - 0.5f;
        const float y = ly * fH - 0.5f;
        const float x0 = floorf(x), y0 = floorf(y);
        const float wx1 = x - x0, wy1 = y - y0;
        const float wx0 = 1.f - wx1, wy0 = 1.f - wy1;
        const int ix0 = (int)x0, iy0 = (int)y0;
        const int ix1 = ix0 + 1, iy1 = iy0 + 1;

        const float vx0 = (ix0 >= 0 && ix0 < Wl) ? 1.f : 0.f;
        const float vx1 = (ix1 >= 0 && ix1 < Wl) ? 1.f : 0.f;
        const float vy0 = (iy0 >= 0 && iy0 < Hl) ? 1.f : 0.f;
        const float vy1 = (iy1 >= 0 && iy1 < Hl) ? 1.f : 0.f;

        const int cx0 = min(max(ix0, 0), Wl - 1);
        const int cx1 = min(max(ix1, 0), Wl - 1);
        const int cy0 = min(max(iy0, 0), Hl - 1);
        const int cy1 = min(max(iy1, 0), Hl - 1);

        swi[h][p][0] = wx0 * wy0 * vx0 * vy0 * aw;
        swi[h][p][1] = wx1 * wy0 * vx1 * vy0 * aw;
        swi[h][p][2] = wx0 * wy1 * vx0 * vy1 * aw;
        swi[h][p][3] = wx1 * wy1 * vx1 * vy1 * aw;
        swi[h][p][4] = __int_as_float(base + cy0 * Wl + cx0);
        swi[h][p][5] = __int_as_float(base + cy0 * Wl + cx1);
        swi[h][p][6] = __int_as_float(base + cy1 * Wl + cx0);
        swi[h][p][7] = __int_as_float(base + cy1 * Wl + cx1);
    }
    __syncthreads();

    const int h = tid >> 5;               // 0..7
    const int d = tid & 31;               // 0..31
    const float* valb = value + (size_t)b * S_ * CD_ + h * DH_ + d;

    float acc = 0.f;
#pragma unroll
    for (int p = 0; p < 16; ++p) {
        const float4 w = *reinterpret_cast<const float4*>(&swi[h][p][0]);
        const float4 f = *reinterpret_cast<const float4*>(&swi[h][p][4]);
        const int i0 = __float_as_int(f.x);
        const int i1 = __float_as_int(f.y);
        const int i2 = __float_as_int(f.z);
        const int i3 = __float_as_int(f.w);
        acc += w.x * valb[i0 * CD_];
        acc += w.y * valb[i1 * CD_];
        acc += w.z * valb[i2 * CD_];
        acc += w.w * valb[i3 * CD_];
    }

    outS[(size_t)bq * CD_ + h * DH_ + d] = acc;
}

// ---------------------------------------------------------------------------
extern "C" void kernel_launch(void* const* d_in, const int* in_sizes, int n_in,
                              void* d_out, int out_size, void* d_ws, size_t ws_size,
                              hipStream_t stream)
{
    const float* query        = (const float*)d_in[0];   // [B,Nq,256]
    const float* value_levels = (const float*)d_in[1];   // [B,S,256]
    const float* refp         = (const float*)d_in[2];   // [B,Nq,NL,2]
    // d_in[3] spatial_shapes: compile-time constants, ignored
    const float* W_off  = (const float*)d_in[4];
    const float* b_off  = (const float*)d_in[5];
    const float* W_attn = (const float*)d_in[6];
    const float* b_attn = (const float*)d_in[7];
    const float* W_val  = (const float*)d_in[8];
    const float* b_val  = (const float*)d_in[9];
    const float* W_out  = (const float*)d_in[10];
    const float* b_out  = (const float*)d_in[11];

    float* out = (float*)d_out;
    float* ws  = (float*)d_ws;

    float* ws_value = ws;                                       // B*S*256
    float* ws_off   = ws_value + (size_t)B_ * S_  * CD_;        // B*Nq*256
    float* ws_attn  = ws_off   + (size_t)B_ * NQ_ * CD_;        // B*Nq*128
    float* ws_samp  = ws_attn  + (size_t)B_ * NQ_ * 128;        // B*Nq*256

    const dim3 blk(256);
    const int M_val = B_ * S_;     // 79788
    const int M_q   = B_ * NQ_;    // 32000

    // 1) value projection -> ws_value   [M_val x 256]
    gemm_mfma<<<dim3((M_val + 127) / 128, 2), blk, 0, stream>>>(
        value_levels, W_val, b_val, ws_value, M_val, 256);

    // 2) offsets projection -> ws_off   [M_q x 256]
    gemm_mfma<<<dim3(M_q / 128, 2), blk, 0, stream>>>(
        query, W_off, b_off, ws_off, M_q, 256);

    // 3) attention logits projection -> ws_attn  [M_q x 128]
    gemm_mfma<<<dim3(M_q / 128, 1), blk, 0, stream>>>(
        query, W_attn, b_attn, ws_attn, M_q, 128);

    // 4) fused softmax + bilinear sampling -> ws_samp
    sampler<<<dim3(B_ * NQ_), blk, 0, stream>>>(
        ws_value, ws_off, ws_attn, refp, ws_samp);

    // 5) output projection -> d_out  [M_q x 256]
    gemm_mfma<<<dim3(M_q / 128, 2), blk, 0, stream>>>(
        ws_samp, W_out, b_out, out, M_q, 256);
}

// Round 8
// 347.997 us; speedup vs baseline: 2.4269x; 1.3227x over previous
//
#include <hip/hip_runtime.h>

#define NH_ 8
#define NL_ 4
#define NP_ 4
#define CD_ 256
#define B_  4
#define NQ_ 8000
#define S_  19947

typedef _Float16 half_t;
typedef __attribute__((ext_vector_type(8))) _Float16 f16x8;
typedef __attribute__((ext_vector_type(4))) float    f32x4;
typedef unsigned int u32;

// async global->LDS, 16B per lane; LDS dest = wave-uniform base + lane*16.
__device__ __forceinline__ void gload_lds16(const void* g, void* l) {
    __builtin_amdgcn_global_load_lds(
        (const __attribute__((address_space(1))) u32*)g,
        (__attribute__((address_space(3))) u32*)l, 16, 0, 0);
}

// ---------------------------------------------------------------------------
// fp32 -> f16 convert, float4/half4 vectorized, grid-stride.
// ---------------------------------------------------------------------------
__global__ __launch_bounds__(256)
void cvt_f16(const float* __restrict__ src, half_t* __restrict__ dst, int n4)
{
    for (int i = blockIdx.x * 256 + threadIdx.x; i < n4; i += gridDim.x * 256) {
        const float4 v = reinterpret_cast<const float4*>(src)[i];
        union { half_t h[4]; uint2 u; } p;
        p.h[0] = (half_t)v.x; p.h[1] = (half_t)v.y;
        p.h[2] = (half_t)v.z; p.h[3] = (half_t)v.w;
        reinterpret_cast<uint2*>(dst)[i] = p.u;
    }
}

// ---------------------------------------------------------------------------
// MFMA f16 GEMM, f16 inputs:  C[m,n] = sum_k A[m,k]*W[n,k] + bias[n], K=256.
// A: [M,256] f16 (rows beyond M clamped on load), W: [N,256] f16, N mult of 128.
// 128x128 tile, BK=64, 4 waves (each 64x64 = 4x4 frags of 16x16x32).
// Staging via global_load_lds width-16: LDS dest linear, SOURCE pre-swizzled
// (granule g' = g ^ (row&7)) so swizzled ds_read_b128 is conflict-free
// (both-sides-or-neither, rule 21). Frag read: byte = row*128 +
// ((col*16) ^ ((row&7)<<4)) -- verified 0 bank conflicts in round 7.
// C/D mapping: col = lane&15, row = (lane>>4)*4 + reg  [m89/m91].
// ---------------------------------------------------------------------------
template<typename OutT>
__global__ __launch_bounds__(256)
void gemm_f16(const half_t* __restrict__ A, const half_t* __restrict__ W,
              const float* __restrict__ bias, OutT* __restrict__ Cmat,
              int M, int N)
{
    __shared__ __align__(16) char ldsA[16384];   // 128 rows x 128 B (64 f16)
    __shared__ __align__(16) char ldsB[16384];

    const int tid  = threadIdx.x;
    const int lane = tid & 63;
    const int wave = tid >> 6;
    const int m0 = blockIdx.x * 128;
    const int n0 = blockIdx.y * 128;
    const int wm = (wave >> 1) * 64;
    const int wn = (wave & 1) * 64;
    const int lr = lane & 15;
    const int lg = lane >> 4;

    f32x4 acc[4][4];
#pragma unroll
    for (int i = 0; i < 4; ++i)
#pragma unroll
        for (int j = 0; j < 4; ++j) {
            f32x4 z = {0.f, 0.f, 0.f, 0.f};
            acc[i][j] = z;
        }

    const int Gw = wave * 64 + lane;   // granule id base (i*256 + Gw)

    for (int t = 0; t < 4; ++t) {      // 4 K-steps of 64
#pragma unroll
        for (int i = 0; i < 4; ++i) {
            const int G = i * 256 + Gw;      // 0..1023
            const int r = G >> 3;            // tile row 0..127
            const int g = G & 7;             // 16B granule within row
            const int gs = (g ^ (r & 7)) << 3;   // pre-swizzled source granule (f16 elems)
            const int arow = min(m0 + r, M - 1);
            gload_lds16(A + ((size_t)arow * 256 + t * 64 + gs),
                        ldsA + (i * 256 + wave * 64) * 16);
            const int brow = n0 + r;         // N exact multiple of 128
            gload_lds16(W + ((size_t)brow * 256 + t * 64 + gs),
                        ldsB + (i * 256 + wave * 64) * 16);
        }
        __syncthreads();                     // drains vmcnt -> tiles ready

#pragma unroll
        for (int ks = 0; ks < 2; ++ks) {     // two K=32 sub-steps
            const int col = ks * 4 + lg;     // 16B column 0..7
            f16x8 af[4], bf[4];
#pragma unroll
            for (int i = 0; i < 4; ++i) {
                const int m = wm + i * 16 + lr;
                af[i] = *reinterpret_cast<const f16x8*>(
                    ldsA + m * 128 + ((col * 16) ^ ((m & 7) << 4)));
            }
#pragma unroll
            for (int j = 0; j < 4; ++j) {
                const int n = wn + j * 16 + lr;
                bf[j] = *reinterpret_cast<const f16x8*>(
                    ldsB + n * 128 + ((col * 16) ^ ((n & 7) << 4)));
            }
#pragma unroll
            for (int i = 0; i < 4; ++i)
#pragma unroll
                for (int j = 0; j < 4; ++j)
                    acc[i][j] = __builtin_amdgcn_mfma_f32_16x16x32_f16(af[i], bf[j], acc[i][j], 0, 0, 0);
        }
        __syncthreads();
    }

    // epilogue: C = acc + bias
#pragma unroll
    for (int j = 0; j < 4; ++j) {
        const int n  = n0 + wn + j * 16 + lr;
        const float bn = bias[n];
#pragma unroll
        for (int i = 0; i < 4; ++i) {
            const int mb = m0 + wm + i * 16 + lg * 4;
#pragma unroll
            for (int r = 0; r < 4; ++r) {
                const int m = mb + r;
                if (m < M) Cmat[(size_t)m * N + n] = (OutT)(acc[i][j][r] + bn);
            }
        }
    }
}

// ---------------------------------------------------------------------------
// Fused softmax + bilinear sampling, two-phase.
// Phase 1 (128 thr = 8h x 16p): softmax via 16-lane shfl_xor; folded corner
//   weights + clamped flat indices -> 4 KB LDS. (verified round 7)
// Phase 2 (256 thr = 8h x 2 point-groups x 16 ch-pairs): per point 4 u32
//   gathers (2 f16 channels each) + FMAs; partials combined via LDS.
// value: [B,S,256] f16 (projected). qproj: [B*Nq,384] f32 (0..255 off,
// 256..383 logits). outS: [B*Nq,256] f16.
// ---------------------------------------------------------------------------
__global__ __launch_bounds__(256)
void sampler(const half_t* __restrict__ value,
             const float* __restrict__ qproj,
             const float* __restrict__ refp,
             half_t* __restrict__ outS)
{
    __shared__ __align__(16) float swi[NH_][16][8];  // [0..3]=w, [4..7]=idx
    __shared__ float2 part[NH_][2][16];

    const int bq  = blockIdx.x;
    const int b   = bq / NQ_;
    const int tid = threadIdx.x;

    if (tid < 128) {
        const int h = tid >> 4;
        const int p = tid & 15;          // l*4 + pp
        const int l = p >> 2;
        const float* qrow = qproj + (size_t)bq * 384;

        const float logit = qrow[256 + h * 16 + p];
        float mx = logit;
#pragma unroll
        for (int m = 8; m >= 1; m >>= 1) mx = fmaxf(mx, __shfl_xor(mx, m, 64));
        float e = __expf(logit - mx);
        float ssum = e;
#pragma unroll
        for (int m = 8; m >= 1; m >>= 1) ssum += __shfl_xor(ssum, m, 64);
        const float aw = e / ssum;

        const int   Hs[4] = {100, 50, 25, 13};
        const int   Ws[4] = {150, 75, 38, 19};
        const int   St[4] = {0, 15000, 18750, 19700};
        const int   Hl = Hs[l], Wl = Ws[l], base = St[l];
        const float fW = (float)Wl, fH = (float)Hl;

        const float rx = refp[((size_t)bq * NL_ + l) * 2 + 0];
        const float ry = refp[((size_t)bq * NL_ + l) * 2 + 1];
        const float ox = qrow[h * 32 + p * 2 + 0];
        const float oy = qrow[h * 32 + p * 2 + 1];

        const float lx = rx + ox / fW;   // reference op order
        const float ly = ry + oy / fH;
        const float x = lx * fW - 0.5f;
        const float y = ly * fH - 0.5f;
        const float x0 = floorf(x), y0 = floorf(y);
        const float wx1 = x - x0, wy1 = y - y0;
        const float wx0 = 1.f - wx1, wy0 = 1.f - wy1;
        const int ix0 = (int)x0, iy0 = (int)y0;
        const int ix1 = ix0 + 1, iy1 = iy0 + 1;

        const float vx0 = (ix0 >= 0 && ix0 < Wl) ? 1.f : 0.f;
        const float vx1 = (ix1 >= 0 && ix1 < Wl) ? 1.f : 0.f;
        const float vy0 = (iy0 >= 0 && iy0 < Hl) ? 1.f : 0.f;
        const float vy1 = (iy1 >= 0 && iy1 < Hl) ? 1.f : 0.f;

        const int cx0 = min(max(ix0, 0), Wl - 1);
        const int cx1 = min(max(ix1, 0), Wl - 1);
        const int cy0 = min(max(iy0, 0), Hl - 1);
        const int cy1 = min(max(iy1, 0), Hl - 1);

        swi[h][p][0] = wx0 * wy0 * vx0 * vy0 * aw;
        swi[h][p][1] = wx1 * wy0 * vx1 * vy0 * aw;
        swi[h][p][2] = wx0 * wy1 * vx0 * vy1 * aw;
        swi[h][p][3] = wx1 * wy1 * vx1 * vy1 * aw;
        swi[h][p][4] = __int_as_float(base + cy0 * Wl + cx0);
        swi[h][p][5] = __int_as_float(base + cy0 * Wl + cx1);
        swi[h][p][6] = __int_as_float(base + cy1 * Wl + cx0);
        swi[h][p][7] = __int_as_float(base + cy1 * Wl + cx1);
    }
    __syncthreads();

    const int h = tid >> 5;          // 0..7
    const int g = (tid >> 4) & 1;    // point-group
    const int c = tid & 15;          // channel pair -> d = 2c, 2c+1
    const half_t* valb = value + (size_t)b * S_ * CD_ + h * 32 + c * 2;

    float ax = 0.f, ay = 0.f;
#pragma unroll
    for (int pp = 0; pp < 8; ++pp) {
        const int p = g * 8 + pp;
        const float4 w = *reinterpret_cast<const float4*>(&swi[h][p][0]);
        const float4 f = *reinterpret_cast<const float4*>(&swi[h][p][4]);
        union { u32 u; half_t h2[2]; } q0, q1, q2, q3;
        q0.u = *reinterpret_cast<const u32*>(valb + (size_t)__float_as_int(f.x) * 256);
        q1.u = *reinterpret_cast<const u32*>(valb + (size_t)__float_as_int(f.y) * 256);
        q2.u = *reinterpret_cast<const u32*>(valb + (size_t)__float_as_int(f.z) * 256);
        q3.u = *reinterpret_cast<const u32*>(valb + (size_t)__float_as_int(f.w) * 256);
        ax += w.x * (float)q0.h2[0]; ay += w.x * (float)q0.h2[1];
        ax += w.y * (float)q1.h2[0]; ay += w.y * (float)q1.h2[1];
        ax += w.z * (float)q2.h2[0]; ay += w.z * (float)q2.h2[1];
        ax += w.w * (float)q3.h2[0]; ay += w.w * (float)q3.h2[1];
    }
    part[h][g][c] = make_float2(ax, ay);
    __syncthreads();

    if (g == 0) {
        const float2 a0 = part[h][0][c];
        const float2 a1 = part[h][1][c];
        union { half_t h2[2]; u32 u; } o;
        o.h2[0] = (half_t)(a0.x + a1.x);
        o.h2[1] = (half_t)(a0.y + a1.y);
        reinterpret_cast<u32*>(outS)[(size_t)bq * 128 + h * 16 + c] = o.u;
    }
}

// ---------------------------------------------------------------------------
extern "C" void kernel_launch(void* const* d_in, const int* in_sizes, int n_in,
                              void* d_out, int out_size, void* d_ws, size_t ws_size,
                              hipStream_t stream)
{
    const float* query        = (const float*)d_in[0];   // [B,Nq,256]
    const float* value_levels = (const float*)d_in[1];   // [B,S,256]
    const float* refp         = (const float*)d_in[2];   // [B,Nq,NL,2]
    const float* W_off  = (const float*)d_in[4];
    const float* b_off  = (const float*)d_in[5];
    const float* W_attn = (const float*)d_in[6];
    const float* b_attn = (const float*)d_in[7];
    const float* W_val  = (const float*)d_in[8];
    const float* b_val  = (const float*)d_in[9];
    const float* W_out  = (const float*)d_in[10];
    const float* b_out  = (const float*)d_in[11];

    float* out = (float*)d_out;

    // workspace layout (f16 region then f32 region), ~147.7 MB total
    const size_t NQF = (size_t)B_ * NQ_ * 256;   //  8,192,000
    const size_t NVF = (size_t)B_ * S_  * 256;   // 20,425,728
    half_t* ws_qf16 = (half_t*)d_ws;
    half_t* ws_vf16 = ws_qf16 + NQF;             // reused as samp after val GEMM
    half_t* ws_Wq   = ws_vf16 + NVF;             // 384x256 (off rows 0-255, attn 256-383)
    half_t* ws_Wv   = ws_Wq + 384 * 256;
    half_t* ws_Wo   = ws_Wv + 256 * 256;
    half_t* ws_valC = ws_Wo + 256 * 256;         // [B*S, 256] f16
    float*  ws_qprojC = (float*)(ws_valC + NVF); // [B*Nq, 384] f32
    float*  ws_bias   = ws_qprojC + (size_t)B_ * NQ_ * 384;  // 384 floats

    const dim3 blk(256);
    const int M_val = B_ * S_;     // 79788
    const int M_q   = B_ * NQ_;    // 32000

    // 0) concat biases (d2d async copies are graph-capture safe)
    hipMemcpyAsync(ws_bias,       b_off,  256 * sizeof(float), hipMemcpyDeviceToDevice, stream);
    hipMemcpyAsync(ws_bias + 256, b_attn, 128 * sizeof(float), hipMemcpyDeviceToDevice, stream);

    // 1) fp32 -> f16 conversions
    cvt_f16<<<dim3(2048), blk, 0, stream>>>(query,        ws_qf16, (int)(NQF / 4));
    cvt_f16<<<dim3(2048), blk, 0, stream>>>(value_levels, ws_vf16, (int)(NVF / 4));
    cvt_f16<<<dim3(64),   blk, 0, stream>>>(W_off,  ws_Wq,               16384);
    cvt_f16<<<dim3(32),   blk, 0, stream>>>(W_attn, ws_Wq + 256 * 256,    8192);
    cvt_f16<<<dim3(64),   blk, 0, stream>>>(W_val,  ws_Wv,               16384);
    cvt_f16<<<dim3(64),   blk, 0, stream>>>(W_out,  ws_Wo,               16384);

    // 2) value projection -> ws_valC (f16)
    gemm_f16<half_t><<<dim3((M_val + 127) / 128, 2), blk, 0, stream>>>(
        ws_vf16, ws_Wv, b_val, ws_valC, M_val, 256);

    // 3) fused off+attn projection -> ws_qprojC (f32, N=384)
    gemm_f16<float><<<dim3(M_q / 128, 3), blk, 0, stream>>>(
        ws_qf16, ws_Wq, ws_bias, ws_qprojC, M_q, 384);

    // 4) fused softmax + bilinear sampling -> samp (f16, reuses vf16 region)
    sampler<<<dim3(B_ * NQ_), blk, 0, stream>>>(
        ws_valC, ws_qprojC, refp, ws_vf16);

    // 5) output projection -> d_out (f32)
    gemm_f16<float><<<dim3(M_q / 128, 2), blk, 0, stream>>>(
        ws_vf16, ws_Wo, b_out, out, M_q, 256);
}